// Round 4
// baseline (959.647 us; speedup 1.0000x reference)
//
#include <hip/hip_runtime.h>

#define D_DIM 1024
#define BM 128
#define BN 128
#define BKB 128   // K bytes per LDS stage (fp8 => 128 elements)

typedef unsigned char u8;
typedef __attribute__((ext_vector_type(8))) int int8v;
typedef __attribute__((ext_vector_type(4))) float floatx4;

union frag_u { int4 h[2]; int8v v; };

__device__ __forceinline__ void gl2lds16(const void* g, void* l) {
  __builtin_amdgcn_global_load_lds(
      (const __attribute__((address_space(1))) void*)g,
      (__attribute__((address_space(3))) void*)l, 16, 0, 0);
}

// ---------- prep: fp32 -> fp8 e4m3 + per-row sum of squares (exact fp32) ----------
__global__ __launch_bounds__(256) void prep_kernel(
    const float* __restrict__ X, const float* __restrict__ S,
    u8* __restrict__ Xb, u8* __restrict__ Sb,
    float* __restrict__ x2, float* __restrict__ s2, int Brows) {
  int wid = blockIdx.x * 4 + (threadIdx.x >> 6);
  int lane = threadIdx.x & 63;
  const float* src; u8* dst; float* sq; int r;
  if (wid < Brows) { src = X; dst = Xb; sq = x2; r = wid; }
  else             { src = S; dst = Sb; sq = s2; r = wid - Brows; }
  const float4* p = (const float4*)(src + (size_t)r * D_DIM);
  float4 v[4];
#pragma unroll
  for (int i = 0; i < 4; i++) v[i] = p[lane * 4 + i];
  float ss = 0.f;
  int4 o;
  int* op = (int*)&o;
#pragma unroll
  for (int i = 0; i < 4; i++) {
    ss += v[i].x * v[i].x + v[i].y * v[i].y + v[i].z * v[i].z + v[i].w * v[i].w;
    int w0 = __builtin_amdgcn_cvt_pk_fp8_f32(v[i].x, v[i].y, 0, false);
    w0 = __builtin_amdgcn_cvt_pk_fp8_f32(v[i].z, v[i].w, w0, true);
    op[i] = w0;
  }
  ((int4*)(dst + (size_t)r * D_DIM))[lane] = o;
#pragma unroll
  for (int m = 32; m > 0; m >>= 1) ss += __shfl_xor(ss, m);
  if (lane == 0) sq[r] = ss;
}

// ---------- fused fp8 GEMM (MX rate, unity scales) + partial logsumexp ----------
// 128x128 tile, BK=128 fp8, 4 waves x (64x64 via 4x4 16x16x128 frags).
// LDS XOR-swizzle at 16B granularity; fragment loads batched by half so
// consecutive ds_read_b128 share a bank pattern (the conflict-free order).
__global__ __launch_bounds__(256, 3) void gemm_lse_kernel(
    const u8* __restrict__ Xb, const u8* __restrict__ Sb,
    const float* __restrict__ x2, const float* __restrict__ s2,
    const float* __restrict__ g, float2* __restrict__ part, int nCB) {
  __shared__ alignas(16) u8 As[BM * BKB];
  __shared__ alignas(16) u8 Bs[BN * BKB];
  __shared__ float red_m[BM * 2];
  __shared__ float red_l[BM * 2];

  const int tid = threadIdx.x;
  const int w = tid >> 6, lane = tid & 63;
  const int bx = blockIdx.x, by = blockIdx.y;
  const int row0 = by * BM, col0 = bx * BN;
  const int wm = w >> 1, wn = w & 1;
  const int quad = lane >> 4, l15 = lane & 15;
  const int SC1 = 0x7F7F7F7F;   // E8M0 = 127 -> 2^0 in all bytes

  floatx4 acc[4][4];
#pragma unroll
  for (int i = 0; i < 4; i++)
#pragma unroll
    for (int j = 0; j < 4; j++) acc[i][j] = (floatx4){0.f, 0.f, 0.f, 0.f};

  const int lr = lane >> 3;
  const int pc = ((lane & 7) ^ lr) * 16;    // swizzled source byte offset
  const u8* gA = Xb + (size_t)(row0 + w * 32 + lr) * D_DIM + pc;
  const u8* gB = Sb + (size_t)(col0 + w * 32 + lr) * D_DIM + pc;
  u8* lA = As + (w * 32) * BKB;             // wave-uniform base; HW adds lane*16
  u8* lB = Bs + (w * 32) * BKB;

  const int swz = l15 & 7;
  const int c0 = ((quad * 2) ^ swz) * 16;
  const int c1 = ((quad * 2 + 1) ^ swz) * 16;
  const int rowA = (wm * 64 + l15) * BKB;
  const int rowB = (wn * 64 + l15) * BKB;

  for (int k0 = 0; k0 < D_DIM; k0 += BKB) {
#pragma unroll
    for (int r = 0; r < 4; ++r) {
      gl2lds16(gA + (size_t)(r * 8) * D_DIM + k0, lA + r * 8 * BKB);
      gl2lds16(gB + (size_t)(r * 8) * D_DIM + k0, lB + r * 8 * BKB);
    }
    __syncthreads();
    frag_u fa[4], fb[4];
    // batch all c0-half reads (same bank pattern per lane), then c1-halves
#pragma unroll
    for (int i = 0; i < 4; i++) fa[i].h[0] = *(const int4*)&As[rowA + i * 16 * BKB + c0];
#pragma unroll
    for (int i = 0; i < 4; i++) fb[i].h[0] = *(const int4*)&Bs[rowB + i * 16 * BKB + c0];
#pragma unroll
    for (int i = 0; i < 4; i++) fa[i].h[1] = *(const int4*)&As[rowA + i * 16 * BKB + c1];
#pragma unroll
    for (int i = 0; i < 4; i++) fb[i].h[1] = *(const int4*)&Bs[rowB + i * 16 * BKB + c1];
#pragma unroll
    for (int mi = 0; mi < 4; mi++)
#pragma unroll
      for (int ni = 0; ni < 4; ni++)
        acc[mi][ni] = __builtin_amdgcn_mfma_scale_f32_16x16x128_f8f6f4(
            fa[mi].v, fb[ni].v, acc[mi][ni], 0, 0, 0, SC1, 0, SC1);
    __syncthreads();
  }

  // ---- epilogue: dist -> z = s*dist -> per-row (m,l) over 128 cols ----
  const float sgn = -g[0];
  float x2v[4][4];
#pragma unroll
  for (int mi = 0; mi < 4; mi++)
#pragma unroll
    for (int rg = 0; rg < 4; rg++)
      x2v[mi][rg] = x2[row0 + wm * 64 + mi * 16 + quad * 4 + rg];
  float s2v[4];
#pragma unroll
  for (int ni = 0; ni < 4; ni++) s2v[ni] = s2[col0 + wn * 64 + ni * 16 + l15];

#pragma unroll
  for (int mi = 0; mi < 4; mi++) {
#pragma unroll
    for (int rg = 0; rg < 4; rg++) {
      float zv[4];
      float mr = -3.4e38f;
#pragma unroll
      for (int ni = 0; ni < 4; ni++) {
        float dist = x2v[mi][rg] + s2v[ni] - 2.f * acc[mi][ni][rg];
        dist = fmaxf(dist, 0.f);
        float z = sgn * dist;
        zv[ni] = z;
        mr = fmaxf(mr, z);
      }
      float lr2 = 0.f;
#pragma unroll
      for (int ni = 0; ni < 4; ni++) lr2 += __expf(zv[ni] - mr);
#pragma unroll
      for (int mask = 1; mask < 16; mask <<= 1) {
        float mo = __shfl_xor(mr, mask);
        float lo = __shfl_xor(lr2, mask);
        float mn = fmaxf(mr, mo);
        lr2 = lr2 * __expf(mr - mn) + lo * __expf(mo - mn);
        mr = mn;
      }
      if (l15 == 0) {
        int rl = wm * 64 + mi * 16 + quad * 4 + rg;
        red_m[rl * 2 + wn] = mr;
        red_l[rl * 2 + wn] = lr2;
      }
    }
  }
  __syncthreads();
  if (tid < BM) {
    float ma = red_m[tid * 2 + 0], la = red_l[tid * 2 + 0];
    float mb = red_m[tid * 2 + 1], lb = red_l[tid * 2 + 1];
    float mn = fmaxf(ma, mb);
    float l = la * __expf(ma - mn) + lb * __expf(mb - mn);
    part[(size_t)(row0 + tid) * nCB + bx] = make_float2(mn, l);
  }
}

// ---------- finalize: merge 128 partials per row -> output ----------
__global__ __launch_bounds__(256) void finalize_kernel(
    const float2* __restrict__ part, const float* __restrict__ g,
    float* __restrict__ out, int nCB, int Ntot) {
  int w = threadIdx.x >> 6, lane = threadIdx.x & 63;
  int row = blockIdx.x * 4 + w;
  const float2* p = part + (size_t)row * nCB;
  float2 a = p[lane];
  float2 b = p[lane + 64];
  float m = fmaxf(a.x, b.x);
  float l = a.y * __expf(a.x - m) + b.y * __expf(b.x - m);
#pragma unroll
  for (int mask = 1; mask < 64; mask <<= 1) {
    float mo = __shfl_xor(m, mask);
    float lo = __shfl_xor(l, mask);
    float mn = fmaxf(m, mo);
    l = l * __expf(m - mn) + lo * __expf(mo - mn);
    m = mn;
  }
  if (lane == 0) {
    float sgn = -g[0];
    out[row] = (m + logf(l) - logf((float)Ntot)) / sgn;
  }
}

extern "C" void kernel_launch(void* const* d_in, const int* in_sizes, int n_in,
                              void* d_out, int out_size, void* d_ws, size_t ws_size,
                              hipStream_t stream) {
  const float* X = (const float*)d_in[0];
  const float* S = (const float*)d_in[1];
  const float* g = (const float*)d_in[2];
  float* out = (float*)d_out;
  const int Bt = in_sizes[0] / D_DIM;   // 4096
  const int Nt = in_sizes[1] / D_DIM;   // 16384
  const int nCB = Nt / BN;              // 128

  char* ws = (char*)d_ws;
  size_t off = 0;
  float2* part = (float2*)(ws + off); off += (size_t)Bt * nCB * sizeof(float2); // 4 MB
  float* x2 = (float*)(ws + off);     off += (size_t)Bt * sizeof(float);
  float* s2 = (float*)(ws + off);     off += (size_t)Nt * sizeof(float);
  off = (off + 255) & ~(size_t)255;
  u8* Xb = (u8*)(ws + off); off += (size_t)Bt * D_DIM;   // 4 MB
  u8* Sb = (u8*)(ws + off); off += (size_t)Nt * D_DIM;   // 16 MB

  prep_kernel<<<(Bt + Nt) / 4, 256, 0, stream>>>(X, S, Xb, Sb, x2, s2, Bt);
  dim3 grid(nCB, Bt / BM);
  gemm_lse_kernel<<<grid, 256, 0, stream>>>(Xb, Sb, x2, s2, g, part, nCB);
  finalize_kernel<<<Bt / 4, 256, 0, stream>>>(part, g, out, nCB, Nt);
}

// Round 5
// 434.969 us; speedup vs baseline: 2.2062x; 2.2062x over previous
//
#include <hip/hip_runtime.h>

#define D_DIM 1024
#define BM 128
#define BN 128
#define BKB 128   // K bytes per LDS stage (fp8 => 128 elements)

typedef unsigned char u8;
typedef __attribute__((ext_vector_type(8))) int int8v;
typedef __attribute__((ext_vector_type(4))) float floatx4;

union frag_u { int4 h[2]; int8v v; };

__device__ __forceinline__ void gl2lds16(const void* g, void* l) {
  __builtin_amdgcn_global_load_lds(
      (const __attribute__((address_space(1))) void*)g,
      (__attribute__((address_space(3))) void*)l, 16, 0, 0);
}

// ---------- prep: fp32 -> fp8 e4m3 + per-row sum of squares (exact fp32) ----------
__global__ __launch_bounds__(256) void prep_kernel(
    const float* __restrict__ X, const float* __restrict__ S,
    u8* __restrict__ Xb, u8* __restrict__ Sb,
    float* __restrict__ x2, float* __restrict__ s2, int Brows) {
  int wid = blockIdx.x * 4 + (threadIdx.x >> 6);
  int lane = threadIdx.x & 63;
  const float* src; u8* dst; float* sq; int r;
  if (wid < Brows) { src = X; dst = Xb; sq = x2; r = wid; }
  else             { src = S; dst = Sb; sq = s2; r = wid - Brows; }
  const float4* p = (const float4*)(src + (size_t)r * D_DIM);
  float4 v[4];
#pragma unroll
  for (int i = 0; i < 4; i++) v[i] = p[lane * 4 + i];
  float ss = 0.f;
  int4 o;
  int* op = (int*)&o;
#pragma unroll
  for (int i = 0; i < 4; i++) {
    ss += v[i].x * v[i].x + v[i].y * v[i].y + v[i].z * v[i].z + v[i].w * v[i].w;
    int w0 = __builtin_amdgcn_cvt_pk_fp8_f32(v[i].x, v[i].y, 0, false);
    w0 = __builtin_amdgcn_cvt_pk_fp8_f32(v[i].z, v[i].w, w0, true);
    op[i] = w0;
  }
  ((int4*)(dst + (size_t)r * D_DIM))[lane] = o;
#pragma unroll
  for (int m = 32; m > 0; m >>= 1) ss += __shfl_xor(ss, m);
  if (lane == 0) sq[r] = ss;
}

// ---------- fused fp8 GEMM (MX rate, unity scales) + partial logsumexp ----------
// 512 threads = 8 waves. Block tile 128x128, BK=128 fp8.
// Wave (wm=w>>2, wn=w&3) owns a 64x32 sub-tile = 4x2 of 16x16x128 frags:
// acc 32 regs, live frags 24 regs -> target VGPR <= 128 for 2 blocks/CU.
// Waves 0-3 stage As, waves 4-7 stage Bs (4 gl2lds width-16 each).
// LDS XOR-swizzle at 16B chunks: phys chunk = logical ^ (row & 7).
__global__ __launch_bounds__(512) void gemm_lse_kernel(
    const u8* __restrict__ Xb, const u8* __restrict__ Sb,
    const float* __restrict__ x2, const float* __restrict__ s2,
    const float* __restrict__ g, float2* __restrict__ part, int nCB) {
  __shared__ alignas(16) u8 As[BM * BKB];
  __shared__ alignas(16) u8 Bs[BN * BKB];
  __shared__ float red_m[BM * 4];
  __shared__ float red_l[BM * 4];

  const int tid = threadIdx.x;
  const int w = tid >> 6, lane = tid & 63;
  const int bx = blockIdx.x, by = blockIdx.y;
  const int row0 = by * BM, col0 = bx * BN;
  const int wm = w >> 2, wn = w & 3;
  const int quad = lane >> 4, l15 = lane & 15;
  const int SC1 = 0x7F7F7F7F;   // E8M0 = 127 -> 2^0 in all bytes

  floatx4 acc[4][2];
#pragma unroll
  for (int i = 0; i < 4; i++)
#pragma unroll
    for (int j = 0; j < 2; j++) acc[i][j] = (floatx4){0.f, 0.f, 0.f, 0.f};

  // staging: wave w<4 covers As rows w*32..+31; w>=4 covers Bs rows (w-4)*32..+31.
  // lane (lr = lane>>3, p = lane&7) sources logical chunk p^lr (XOR swizzle).
  const int lr = lane >> 3;
  const int pc = ((lane & 7) ^ lr) * 16;
  const u8* gsrc;
  u8* ldst;
  if (w < 4) {
    gsrc = Xb + (size_t)(row0 + w * 32 + lr) * D_DIM + pc;
    ldst = As + (w * 32) * BKB;
  } else {
    gsrc = Sb + (size_t)(col0 + (w - 4) * 32 + lr) * D_DIM + pc;
    ldst = Bs + ((w - 4) * 32) * BKB;
  }

  const int swz = l15 & 7;
  const int c0 = ((quad * 2) ^ swz) * 16;
  const int c1 = ((quad * 2 + 1) ^ swz) * 16;
  const int rowA = (wm * 64 + l15) * BKB;
  const int rowB = (wn * 32 + l15) * BKB;

  for (int k0 = 0; k0 < D_DIM; k0 += BKB) {
#pragma unroll
    for (int r = 0; r < 4; ++r)
      gl2lds16(gsrc + (size_t)(r * 8) * D_DIM + k0, ldst + r * 8 * BKB);
    __syncthreads();
    frag_u fb[2];
#pragma unroll
    for (int ni = 0; ni < 2; ni++) {
      fb[ni].h[0] = *(const int4*)&Bs[rowB + ni * 16 * BKB + c0];
      fb[ni].h[1] = *(const int4*)&Bs[rowB + ni * 16 * BKB + c1];
    }
#pragma unroll
    for (int mi = 0; mi < 4; mi++) {
      frag_u fa;
      fa.h[0] = *(const int4*)&As[rowA + mi * 16 * BKB + c0];
      fa.h[1] = *(const int4*)&As[rowA + mi * 16 * BKB + c1];
      acc[mi][0] = __builtin_amdgcn_mfma_scale_f32_16x16x128_f8f6f4(
          fa.v, fb[0].v, acc[mi][0], 0, 0, 0, SC1, 0, SC1);
      acc[mi][1] = __builtin_amdgcn_mfma_scale_f32_16x16x128_f8f6f4(
          fa.v, fb[1].v, acc[mi][1], 0, 0, 0, SC1, 0, SC1);
    }
    __syncthreads();
  }

  // ---- epilogue: dist -> z = s*dist -> per-row (m,l) over this 32-col strip ----
  const float sgn = -g[0];
  float x2v[4][4];
#pragma unroll
  for (int mi = 0; mi < 4; mi++)
#pragma unroll
    for (int rg = 0; rg < 4; rg++)
      x2v[mi][rg] = x2[row0 + wm * 64 + mi * 16 + quad * 4 + rg];
  float s2v[2];
#pragma unroll
  for (int ni = 0; ni < 2; ni++) s2v[ni] = s2[col0 + wn * 32 + ni * 16 + l15];

#pragma unroll
  for (int mi = 0; mi < 4; mi++) {
#pragma unroll
    for (int rg = 0; rg < 4; rg++) {
      float zv[2];
      float mr = -3.4e38f;
#pragma unroll
      for (int ni = 0; ni < 2; ni++) {
        float dist = x2v[mi][rg] + s2v[ni] - 2.f * acc[mi][ni][rg];
        dist = fmaxf(dist, 0.f);
        float z = sgn * dist;
        zv[ni] = z;
        mr = fmaxf(mr, z);
      }
      float lr2 = __expf(zv[0] - mr) + __expf(zv[1] - mr);
#pragma unroll
      for (int mask = 1; mask < 16; mask <<= 1) {
        float mo = __shfl_xor(mr, mask);
        float lo = __shfl_xor(lr2, mask);
        float mn = fmaxf(mr, mo);
        lr2 = lr2 * __expf(mr - mn) + lo * __expf(mo - mn);
        mr = mn;
      }
      if (l15 == 0) {
        int rl = wm * 64 + mi * 16 + quad * 4 + rg;
        red_m[rl * 4 + wn] = mr;
        red_l[rl * 4 + wn] = lr2;
      }
    }
  }
  __syncthreads();
  if (tid < BM) {
    float m01 = fmaxf(red_m[tid * 4 + 0], red_m[tid * 4 + 1]);
    float l01 = red_l[tid * 4 + 0] * __expf(red_m[tid * 4 + 0] - m01) +
                red_l[tid * 4 + 1] * __expf(red_m[tid * 4 + 1] - m01);
    float m23 = fmaxf(red_m[tid * 4 + 2], red_m[tid * 4 + 3]);
    float l23 = red_l[tid * 4 + 2] * __expf(red_m[tid * 4 + 2] - m23) +
                red_l[tid * 4 + 3] * __expf(red_m[tid * 4 + 3] - m23);
    float mn = fmaxf(m01, m23);
    float l = l01 * __expf(m01 - mn) + l23 * __expf(m23 - mn);
    part[(size_t)(row0 + tid) * nCB + bx] = make_float2(mn, l);
  }
}

// ---------- finalize: merge 128 partials per row -> output ----------
__global__ __launch_bounds__(256) void finalize_kernel(
    const float2* __restrict__ part, const float* __restrict__ g,
    float* __restrict__ out, int nCB, int Ntot) {
  int w = threadIdx.x >> 6, lane = threadIdx.x & 63;
  int row = blockIdx.x * 4 + w;
  const float2* p = part + (size_t)row * nCB;
  float2 a = p[lane];
  float2 b = p[lane + 64];
  float m = fmaxf(a.x, b.x);
  float l = a.y * __expf(a.x - m) + b.y * __expf(b.x - m);
#pragma unroll
  for (int mask = 1; mask < 64; mask <<= 1) {
    float mo = __shfl_xor(m, mask);
    float lo = __shfl_xor(l, mask);
    float mn = fmaxf(m, mo);
    l = l * __expf(m - mn) + lo * __expf(mo - mn);
    m = mn;
  }
  if (lane == 0) {
    float sgn = -g[0];
    out[row] = (m + logf(l) - logf((float)Ntot)) / sgn;
  }
}

extern "C" void kernel_launch(void* const* d_in, const int* in_sizes, int n_in,
                              void* d_out, int out_size, void* d_ws, size_t ws_size,
                              hipStream_t stream) {
  const float* X = (const float*)d_in[0];
  const float* S = (const float*)d_in[1];
  const float* g = (const float*)d_in[2];
  float* out = (float*)d_out;
  const int Bt = in_sizes[0] / D_DIM;   // 4096
  const int Nt = in_sizes[1] / D_DIM;   // 16384
  const int nCB = Nt / BN;              // 128

  char* ws = (char*)d_ws;
  size_t off = 0;
  float2* part = (float2*)(ws + off); off += (size_t)Bt * nCB * sizeof(float2); // 4 MB
  float* x2 = (float*)(ws + off);     off += (size_t)Bt * sizeof(float);
  float* s2 = (float*)(ws + off);     off += (size_t)Nt * sizeof(float);
  off = (off + 255) & ~(size_t)255;
  u8* Xb = (u8*)(ws + off); off += (size_t)Bt * D_DIM;   // 4 MB
  u8* Sb = (u8*)(ws + off); off += (size_t)Nt * D_DIM;   // 16 MB

  prep_kernel<<<(Bt + Nt) / 4, 256, 0, stream>>>(X, S, Xb, Sb, x2, s2, Bt);
  dim3 grid(nCB, Bt / BM);
  gemm_lse_kernel<<<grid, 512, 0, stream>>>(Xb, Sb, x2, s2, g, part, nCB);
  finalize_kernel<<<Bt / 4, 256, 0, stream>>>(part, g, out, nCB, Nt);
}

// Round 6
// 406.957 us; speedup vs baseline: 2.3581x; 1.0688x over previous
//
#include <hip/hip_runtime.h>

#define D_DIM 1024
#define BM 128
#define BN 128
#define BKB 128   // K bytes per LDS stage (fp8 => 128 elements)

typedef unsigned char u8;
typedef __attribute__((ext_vector_type(8))) int int8v;
typedef __attribute__((ext_vector_type(16))) float floatx16;

union frag_u { int4 h[2]; int8v v; };

__device__ __forceinline__ void gl2lds16(const void* g, void* l) {
  __builtin_amdgcn_global_load_lds(
      (const __attribute__((address_space(1))) void*)g,
      (__attribute__((address_space(3))) void*)l, 16, 0, 0);
}

// ---------- prep: fp32 -> fp8 e4m3 + per-row sum of squares (exact fp32) ----------
__global__ __launch_bounds__(256) void prep_kernel(
    const float* __restrict__ X, const float* __restrict__ S,
    u8* __restrict__ Xb, u8* __restrict__ Sb,
    float* __restrict__ x2, float* __restrict__ s2, int Brows) {
  int wid = blockIdx.x * 4 + (threadIdx.x >> 6);
  int lane = threadIdx.x & 63;
  const float* src; u8* dst; float* sq; int r;
  if (wid < Brows) { src = X; dst = Xb; sq = x2; r = wid; }
  else             { src = S; dst = Sb; sq = s2; r = wid - Brows; }
  const float4* p = (const float4*)(src + (size_t)r * D_DIM);
  float4 v[4];
#pragma unroll
  for (int i = 0; i < 4; i++) v[i] = p[lane * 4 + i];
  float ss = 0.f;
  int4 o;
  int* op = (int*)&o;
#pragma unroll
  for (int i = 0; i < 4; i++) {
    ss += v[i].x * v[i].x + v[i].y * v[i].y + v[i].z * v[i].z + v[i].w * v[i].w;
    int w0 = __builtin_amdgcn_cvt_pk_fp8_f32(v[i].x, v[i].y, 0, false);
    w0 = __builtin_amdgcn_cvt_pk_fp8_f32(v[i].z, v[i].w, w0, true);
    op[i] = w0;
  }
  ((int4*)(dst + (size_t)r * D_DIM))[lane] = o;
#pragma unroll
  for (int m = 32; m > 0; m >>= 1) ss += __shfl_xor(ss, m);
  if (lane == 0) sq[r] = ss;
}

// ---------- fused fp8 GEMM (MX rate, unity scales, 32x32x64 frags) + LSE ----------
// 256 threads = 4 waves (2x2). Block tile 128x128, BK=128 fp8.
// Wave owns 64x64 = 2x2 of 32x32x64: acc = 2x2 floatx16 (AGPR-eligible),
// live frags fb[2]+fa = 24 regs -> target ~130 arch VGPR, >=2 waves/SIMD.
// LDS XOR-swizzle at 16B chunks: phys chunk = logical ^ (row & 7).
// C/D layout (verified): col = lane&31, row = (reg&3) + 8*(reg>>2) + 4*(lane>>5).
__global__ __launch_bounds__(256) void gemm_lse_kernel(
    const u8* __restrict__ Xb, const u8* __restrict__ Sb,
    const float* __restrict__ x2, const float* __restrict__ s2,
    const float* __restrict__ g, float2* __restrict__ part, int nCB) {
  __shared__ alignas(16) u8 As[BM * BKB];
  __shared__ alignas(16) u8 Bs[BN * BKB];
  __shared__ float red_m[BM * 2];
  __shared__ float red_l[BM * 2];
  __shared__ float x2s[BM];
  __shared__ float s2s[BN];

  const int tid = threadIdx.x;
  const int w = tid >> 6, lane = tid & 63;
  const int bx = blockIdx.x, by = blockIdx.y;
  const int row0 = by * BM, col0 = bx * BN;
  const int wm = w >> 1, wn = w & 1;
  const int l31 = lane & 31, h = lane >> 5;
  const int SC1 = 0x7F7F7F7F;   // E8M0 = 127 -> 2^0 in all bytes

  floatx16 acc[2][2];
#pragma unroll
  for (int i = 0; i < 2; i++)
#pragma unroll
    for (int j = 0; j < 2; j++)
#pragma unroll
      for (int r = 0; r < 16; r++) acc[i][j][r] = 0.f;

  // stage x2/s2 slices (covered by the first __syncthreads below)
  if (tid < BM) x2s[tid] = x2[row0 + tid];
  else if (tid < BM + BN) s2s[tid - BM] = s2[col0 + tid - BM];

  // staging: wave w covers rows w*32..+31 of both As and Bs (4 r-steps x 8 rows).
  // lane (lr = lane>>3, p = lane&7) sources logical chunk p^lr (XOR swizzle).
  const int lr = lane >> 3;
  const int pc = ((lane & 7) ^ lr) * 16;
  const u8* gA = Xb + (size_t)(row0 + w * 32 + lr) * D_DIM + pc;
  const u8* gB = Sb + (size_t)(col0 + w * 32 + lr) * D_DIM + pc;
  u8* lA = As + (w * 32) * BKB;   // wave-uniform base; HW adds lane*16
  u8* lB = Bs + (w * 32) * BKB;

  // fragment read addressing: row = (tile64 base) + l31; key = row&7 = lane&7.
  const int key = lane & 7;
  const int rowA = (wm * 64 + l31) * BKB;
  const int rowB = (wn * 64 + l31) * BKB;

  for (int k0 = 0; k0 < D_DIM; k0 += BKB) {
#pragma unroll
    for (int r = 0; r < 4; ++r) {
      gl2lds16(gA + (size_t)(r * 8) * D_DIM + k0, lA + r * 8 * BKB);
      gl2lds16(gB + (size_t)(r * 8) * D_DIM + k0, lB + r * 8 * BKB);
    }
    __syncthreads();
#pragma unroll
    for (int ks = 0; ks < 2; ++ks) {
      const int c0 = ((ks * 4 + h * 2 + 0) ^ key) * 16;
      const int c1 = ((ks * 4 + h * 2 + 1) ^ key) * 16;
      frag_u fb[2];
#pragma unroll
      for (int ni = 0; ni < 2; ni++) {
        fb[ni].h[0] = *(const int4*)&Bs[rowB + ni * 32 * BKB + c0];
        fb[ni].h[1] = *(const int4*)&Bs[rowB + ni * 32 * BKB + c1];
      }
#pragma unroll
      for (int mi = 0; mi < 2; mi++) {
        frag_u fa;
        fa.h[0] = *(const int4*)&As[rowA + mi * 32 * BKB + c0];
        fa.h[1] = *(const int4*)&As[rowA + mi * 32 * BKB + c1];
        acc[mi][0] = __builtin_amdgcn_mfma_scale_f32_32x32x64_f8f6f4(
            fa.v, fb[0].v, acc[mi][0], 0, 0, 0, SC1, 0, SC1);
        acc[mi][1] = __builtin_amdgcn_mfma_scale_f32_32x32x64_f8f6f4(
            fa.v, fb[1].v, acc[mi][1], 0, 0, 0, SC1, 0, SC1);
      }
    }
    __syncthreads();
  }

  // ---- epilogue: dist -> z -> per-row (m,l) over this wave's 64 cols ----
  const float sgn = -g[0];
  float s2v[2];
#pragma unroll
  for (int ni = 0; ni < 2; ni++) s2v[ni] = s2s[wn * 64 + ni * 32 + l31];

#pragma unroll
  for (int mi = 0; mi < 2; mi++) {
#pragma unroll
    for (int r = 0; r < 16; r++) {
      const int rl = wm * 64 + mi * 32 + (r & 3) + 8 * (r >> 2) + 4 * h;
      const float x2v = x2s[rl];
      float z0 = sgn * fmaxf(x2v + s2v[0] - 2.f * acc[mi][0][r], 0.f);
      float z1 = sgn * fmaxf(x2v + s2v[1] - 2.f * acc[mi][1][r], 0.f);
      float mr = fmaxf(z0, z1);
      float lr2 = __expf(z0 - mr) + __expf(z1 - mr);
#pragma unroll
      for (int mask = 1; mask < 32; mask <<= 1) {
        float mo = __shfl_xor(mr, mask);
        float lo = __shfl_xor(lr2, mask);
        float mn = fmaxf(mr, mo);
        lr2 = lr2 * __expf(mr - mn) + lo * __expf(mo - mn);
        mr = mn;
      }
      if (l31 == 0) {
        red_m[rl * 2 + wn] = mr;
        red_l[rl * 2 + wn] = lr2;
      }
    }
  }
  __syncthreads();
  if (tid < BM) {
    float ma = red_m[tid * 2 + 0], la = red_l[tid * 2 + 0];
    float mb = red_m[tid * 2 + 1], lb = red_l[tid * 2 + 1];
    float mn = fmaxf(ma, mb);
    float l = la * __expf(ma - mn) + lb * __expf(mb - mn);
    part[(size_t)(row0 + tid) * nCB + bx] = make_float2(mn, l);
  }
}

// ---------- finalize: merge 128 partials per row -> output ----------
__global__ __launch_bounds__(256) void finalize_kernel(
    const float2* __restrict__ part, const float* __restrict__ g,
    float* __restrict__ out, int nCB, int Ntot) {
  int w = threadIdx.x >> 6, lane = threadIdx.x & 63;
  int row = blockIdx.x * 4 + w;
  const float2* p = part + (size_t)row * nCB;
  float2 a = p[lane];
  float2 b = p[lane + 64];
  float m = fmaxf(a.x, b.x);
  float l = a.y * __expf(a.x - m) + b.y * __expf(b.x - m);
#pragma unroll
  for (int mask = 1; mask < 64; mask <<= 1) {
    float mo = __shfl_xor(m, mask);
    float lo = __shfl_xor(l, mask);
    float mn = fmaxf(m, mo);
    l = l * __expf(m - mn) + lo * __expf(mo - mn);
    m = mn;
  }
  if (lane == 0) {
    float sgn = -g[0];
    out[row] = (m + logf(l) - logf((float)Ntot)) / sgn;
  }
}

extern "C" void kernel_launch(void* const* d_in, const int* in_sizes, int n_in,
                              void* d_out, int out_size, void* d_ws, size_t ws_size,
                              hipStream_t stream) {
  const float* X = (const float*)d_in[0];
  const float* S = (const float*)d_in[1];
  const float* g = (const float*)d_in[2];
  float* out = (float*)d_out;
  const int Bt = in_sizes[0] / D_DIM;   // 4096
  const int Nt = in_sizes[1] / D_DIM;   // 16384
  const int nCB = Nt / BN;              // 128

  char* ws = (char*)d_ws;
  size_t off = 0;
  float2* part = (float2*)(ws + off); off += (size_t)Bt * nCB * sizeof(float2); // 4 MB
  float* x2 = (float*)(ws + off);     off += (size_t)Bt * sizeof(float);
  float* s2 = (float*)(ws + off);     off += (size_t)Nt * sizeof(float);
  off = (off + 255) & ~(size_t)255;
  u8* Xb = (u8*)(ws + off); off += (size_t)Bt * D_DIM;   // 4 MB
  u8* Sb = (u8*)(ws + off); off += (size_t)Nt * D_DIM;   // 16 MB

  prep_kernel<<<(Bt + Nt) / 4, 256, 0, stream>>>(X, S, Xb, Sb, x2, s2, Bt);
  dim3 grid(nCB, Bt / BM);
  gemm_lse_kernel<<<grid, 256, 0, stream>>>(Xb, Sb, x2, s2, g, part, nCB);
  finalize_kernel<<<Bt / 4, 256, 0, stream>>>(part, g, out, nCB, Nt);
}

// Round 7
// 250.895 us; speedup vs baseline: 3.8249x; 1.6220x over previous
//
#include <hip/hip_runtime.h>

#define D_DIM 1024
#define BM 128
#define BN 128
#define BKB 128   // K bytes per LDS stage (fp8 => 128 elements = 4 MFMA k-slices)

typedef unsigned char u8;
typedef __attribute__((ext_vector_type(4))) float floatx4;

union frag_u { int4 h; long l[2]; };

__device__ __forceinline__ void gl2lds16(const void* g, void* l) {
  __builtin_amdgcn_global_load_lds(
      (const __attribute__((address_space(1))) void*)g,
      (__attribute__((address_space(3))) void*)l, 16, 0, 0);
}

// ---------- prep: fp32 -> fp8 e4m3 + per-row sum of squares (exact fp32) ----------
// wave-per-row, coalesced float4 reads (lane + i*64), coalesced int stores.
__global__ __launch_bounds__(256) void prep_kernel(
    const float* __restrict__ X, const float* __restrict__ S,
    u8* __restrict__ Xb, u8* __restrict__ Sb,
    float* __restrict__ x2, float* __restrict__ s2, int Brows) {
  int wid = blockIdx.x * 4 + (threadIdx.x >> 6);
  int lane = threadIdx.x & 63;
  const float* src; u8* dst; float* sq; int r;
  if (wid < Brows) { src = X; dst = Xb; sq = x2; r = wid; }
  else             { src = S; dst = Sb; sq = s2; r = wid - Brows; }
  const float4* p = (const float4*)(src + (size_t)r * D_DIM);
  float4 v[4];
#pragma unroll
  for (int i = 0; i < 4; i++) v[i] = p[lane + i * 64];
  float ss = 0.f;
  int* q = (int*)(dst + (size_t)r * D_DIM);
#pragma unroll
  for (int i = 0; i < 4; i++) {
    ss += v[i].x * v[i].x + v[i].y * v[i].y + v[i].z * v[i].z + v[i].w * v[i].w;
    int w0 = __builtin_amdgcn_cvt_pk_fp8_f32(v[i].x, v[i].y, 0, false);
    w0 = __builtin_amdgcn_cvt_pk_fp8_f32(v[i].z, v[i].w, w0, true);
    q[lane + i * 64] = w0;   // 4B per float4, coalesced
  }
#pragma unroll
  for (int m = 32; m > 0; m >>= 1) ss += __shfl_xor(ss, m);
  if (lane == 0) sq[r] = ss;
}

// ---------- fused fp8 GEMM (non-scaled, bf16 rate, half traffic) + LSE ----------
// R2's exact geometry: 128x128 tile, BK=128 B rows, 4 waves x 64x64 (4x4 frags
// of 16x16). Each 16B b128 fragment read feeds TWO 16x16x32_fp8_fp8 MFMAs
// (bytes 0-7 and 8-15); chunk addressing identical to R2's zero-conflict
// pattern: phys chunk = ((half*4 + quad) ^ (row&7)).
__global__ __launch_bounds__(256) void gemm_lse_kernel(
    const u8* __restrict__ Xb, const u8* __restrict__ Sb,
    const float* __restrict__ x2, const float* __restrict__ s2,
    const float* __restrict__ g, float2* __restrict__ part, int nCB) {
  __shared__ alignas(16) u8 As[BM * BKB];
  __shared__ alignas(16) u8 Bs[BN * BKB];
  __shared__ float red_m[BM * 2];
  __shared__ float red_l[BM * 2];

  const int tid = threadIdx.x;
  const int w = tid >> 6, lane = tid & 63;
  const int bx = blockIdx.x, by = blockIdx.y;
  const int row0 = by * BM, col0 = bx * BN;
  const int wm = w >> 1, wn = w & 1;
  const int quad = lane >> 4, l15 = lane & 15;

  floatx4 acc[4][4];
#pragma unroll
  for (int i = 0; i < 4; i++)
#pragma unroll
    for (int j = 0; j < 4; j++) acc[i][j] = (floatx4){0.f, 0.f, 0.f, 0.f};

  // staging (proven R3 pattern): wave w covers rows w*32..+31 of As AND Bs.
  // lane (lr=lane>>3, p=lane&7) sources logical chunk p^lr -> XOR-swizzled tile.
  const int lr = lane >> 3;
  const int pc = ((lane & 7) ^ lr) * 16;
  const u8* gA = Xb + (size_t)(row0 + w * 32 + lr) * D_DIM + pc;
  const u8* gB = Sb + (size_t)(col0 + w * 32 + lr) * D_DIM + pc;
  u8* lA = As + (w * 32) * BKB;   // wave-uniform base; HW adds lane*16
  u8* lB = Bs + (w * 32) * BKB;

  const int swz = l15 & 7;
  const int rowA = (wm * 64 + l15) * BKB;
  const int rowB = (wn * 64 + l15) * BKB;

  for (int k0 = 0; k0 < D_DIM; k0 += BKB) {
#pragma unroll
    for (int r = 0; r < 4; ++r) {
      gl2lds16(gA + (size_t)(r * 8) * D_DIM + k0, lA + r * 8 * BKB);
      gl2lds16(gB + (size_t)(r * 8) * D_DIM + k0, lB + r * 8 * BKB);
    }
    __syncthreads();
#pragma unroll
    for (int half = 0; half < 2; ++half) {
      const int c = (((half * 4 + quad) ^ swz) * 16);
      frag_u fa[4], fb[4];
#pragma unroll
      for (int mi = 0; mi < 4; mi++)
        fa[mi].h = *(const int4*)&As[rowA + mi * 16 * BKB + c];
#pragma unroll
      for (int ni = 0; ni < 4; ni++)
        fb[ni].h = *(const int4*)&Bs[rowB + ni * 16 * BKB + c];
#pragma unroll
      for (int mi = 0; mi < 4; mi++)
#pragma unroll
        for (int ni = 0; ni < 4; ni++) {
          acc[mi][ni] = __builtin_amdgcn_mfma_f32_16x16x32_fp8_fp8(
              fa[mi].l[0], fb[ni].l[0], acc[mi][ni], 0, 0, 0);
          acc[mi][ni] = __builtin_amdgcn_mfma_f32_16x16x32_fp8_fp8(
              fa[mi].l[1], fb[ni].l[1], acc[mi][ni], 0, 0, 0);
        }
    }
    __syncthreads();
  }

  // ---- epilogue: dist -> z = s*dist -> per-row (m,l) over 128 cols ----
  const float sgn = -g[0];
  float x2v[4][4];
#pragma unroll
  for (int mi = 0; mi < 4; mi++)
#pragma unroll
    for (int rg = 0; rg < 4; rg++)
      x2v[mi][rg] = x2[row0 + wm * 64 + mi * 16 + quad * 4 + rg];
  float s2v[4];
#pragma unroll
  for (int ni = 0; ni < 4; ni++) s2v[ni] = s2[col0 + wn * 64 + ni * 16 + l15];

#pragma unroll
  for (int mi = 0; mi < 4; mi++) {
#pragma unroll
    for (int rg = 0; rg < 4; rg++) {
      float zv[4];
      float mr = -3.4e38f;
#pragma unroll
      for (int ni = 0; ni < 4; ni++) {
        float dist = x2v[mi][rg] + s2v[ni] - 2.f * acc[mi][ni][rg];
        dist = fmaxf(dist, 0.f);
        float z = sgn * dist;
        zv[ni] = z;
        mr = fmaxf(mr, z);
      }
      float lr2 = 0.f;
#pragma unroll
      for (int ni = 0; ni < 4; ni++) lr2 += __expf(zv[ni] - mr);
#pragma unroll
      for (int mask = 1; mask < 16; mask <<= 1) {
        float mo = __shfl_xor(mr, mask);
        float lo = __shfl_xor(lr2, mask);
        float mn = fmaxf(mr, mo);
        lr2 = lr2 * __expf(mr - mn) + lo * __expf(mo - mn);
        mr = mn;
      }
      if (l15 == 0) {
        int rl = wm * 64 + mi * 16 + quad * 4 + rg;
        red_m[rl * 2 + wn] = mr;
        red_l[rl * 2 + wn] = lr2;
      }
    }
  }
  __syncthreads();
  if (tid < BM) {
    float ma = red_m[tid * 2 + 0], la = red_l[tid * 2 + 0];
    float mb = red_m[tid * 2 + 1], lb = red_l[tid * 2 + 1];
    float mn = fmaxf(ma, mb);
    float l = la * __expf(ma - mn) + lb * __expf(mb - mn);
    part[(size_t)(row0 + tid) * nCB + bx] = make_float2(mn, l);
  }
}

// ---------- finalize: merge 128 partials per row -> output ----------
__global__ __launch_bounds__(256) void finalize_kernel(
    const float2* __restrict__ part, const float* __restrict__ g,
    float* __restrict__ out, int nCB, int Ntot) {
  int w = threadIdx.x >> 6, lane = threadIdx.x & 63;
  int row = blockIdx.x * 4 + w;
  const float2* p = part + (size_t)row * nCB;
  float2 a = p[lane];
  float2 b = p[lane + 64];
  float m = fmaxf(a.x, b.x);
  float l = a.y * __expf(a.x - m) + b.y * __expf(b.x - m);
#pragma unroll
  for (int mask = 1; mask < 64; mask <<= 1) {
    float mo = __shfl_xor(m, mask);
    float lo = __shfl_xor(l, mask);
    float mn = fmaxf(m, mo);
    l = l * __expf(m - mn) + lo * __expf(mo - mn);
    m = mn;
  }
  if (lane == 0) {
    float sgn = -g[0];
    out[row] = (m + logf(l) - logf((float)Ntot)) / sgn;
  }
}

extern "C" void kernel_launch(void* const* d_in, const int* in_sizes, int n_in,
                              void* d_out, int out_size, void* d_ws, size_t ws_size,
                              hipStream_t stream) {
  const float* X = (const float*)d_in[0];
  const float* S = (const float*)d_in[1];
  const float* g = (const float*)d_in[2];
  float* out = (float*)d_out;
  const int Bt = in_sizes[0] / D_DIM;   // 4096
  const int Nt = in_sizes[1] / D_DIM;   // 16384
  const int nCB = Nt / BN;              // 128

  char* ws = (char*)d_ws;
  size_t off = 0;
  float2* part = (float2*)(ws + off); off += (size_t)Bt * nCB * sizeof(float2); // 4 MB
  float* x2 = (float*)(ws + off);     off += (size_t)Bt * sizeof(float);
  float* s2 = (float*)(ws + off);     off += (size_t)Nt * sizeof(float);
  off = (off + 255) & ~(size_t)255;
  u8* Xb = (u8*)(ws + off); off += (size_t)Bt * D_DIM;   // 4 MB
  u8* Sb = (u8*)(ws + off); off += (size_t)Nt * D_DIM;   // 16 MB

  prep_kernel<<<(Bt + Nt) / 4, 256, 0, stream>>>(X, S, Xb, Sb, x2, s2, Bt);
  dim3 grid(nCB, Bt / BM);
  gemm_lse_kernel<<<grid, 256, 0, stream>>>(Xb, Sb, x2, s2, g, part, nCB);
  finalize_kernel<<<Bt / 4, 256, 0, stream>>>(part, g, out, nCB, Nt);
}